// Round 11
// baseline (255.767 us; speedup 1.0000x reference)
//
#include <hip/hip_runtime.h>

// B=4, C=256, C8=32, N=4096. fp16 MFMA: 16x16x32 (S, proj), 32x32x16 (PV).
#define BB 4
#define CC 256
#define NN 4096

typedef _Float16 half_t;
typedef __attribute__((ext_vector_type(8))) _Float16 half8;
typedef __attribute__((ext_vector_type(4))) _Float16 half4;
typedef __attribute__((ext_vector_type(4))) float floatx4;
typedef __attribute__((ext_vector_type(16))) float floatx16;

// ---------------------------------------------------------------------------
// cvt_w: cast the six weight matrices to fp16. grid (64, 6).
// ---------------------------------------------------------------------------
__global__ __launch_bounds__(256)
void cvt_w_kernel(const float* __restrict__ Wfx, const float* __restrict__ Wgx,
                  const float* __restrict__ Whx, const float* __restrict__ Wfy,
                  const float* __restrict__ Wgy, const float* __restrict__ Why,
                  half_t* __restrict__ oWfx, half_t* __restrict__ oWgx,
                  half_t* __restrict__ oWhx, half_t* __restrict__ oWfy,
                  half_t* __restrict__ oWgy, half_t* __restrict__ oWhy)
{
    const float* src; half_t* dst; int n;
    switch (blockIdx.y) {
        case 0: src = Wfx; dst = oWfx; n = 32 * CC; break;
        case 1: src = Wgx; dst = oWgx; n = 32 * CC; break;
        case 2: src = Whx; dst = oWhx; n = CC * CC; break;
        case 3: src = Wfy; dst = oWfy; n = 32 * CC; break;
        case 4: src = Wgy; dst = oWgy; n = 32 * CC; break;
        default: src = Why; dst = oWhy; n = CC * CC; break;
    }
    int idx = (blockIdx.x * 256 + threadIdx.x) * 4;
    if (idx >= n) return;
    float4 v = *(const float4*)&src[idx];
    half4 h; h[0] = (half_t)v.x; h[1] = (half_t)v.y; h[2] = (half_t)v.z; h[3] = (half_t)v.w;
    *(half4*)&dst[idx] = h;
}

// ---------------------------------------------------------------------------
// prep (fused transpose_cvt + proj_fg + proj_h): per block, stage
// xT[64n][256c] fp16 in LDS, then compute fT/gT and h (plain [c][n]) for
// this 64-n tile. h epilogue routed through LDS (hs alias of xT) so global
// h stores are 4x coalesced half8 per thread. grid (64, 4, 2). 512 thr.
// ---------------------------------------------------------------------------
__global__ __launch_bounds__(512, 4)
void prep_kernel(const float* __restrict__ x, const float* __restrict__ y,
                 const half_t* __restrict__ Wfx, const half_t* __restrict__ Wgx,
                 const half_t* __restrict__ Whx, const half_t* __restrict__ Wfy,
                 const half_t* __restrict__ Wgy, const half_t* __restrict__ Why,
                 const float* __restrict__ bfx, const float* __restrict__ bgx,
                 const float* __restrict__ bhx, const float* __restrict__ bfy,
                 const float* __restrict__ bgy, const float* __restrict__ bhy,
                 half_t* __restrict__ fxT, half_t* __restrict__ gxT,
                 half_t* __restrict__ hx,
                 half_t* __restrict__ fyT, half_t* __restrict__ gyT,
                 half_t* __restrict__ hy)
{
    __shared__ half_t xT[64][266];   // 34 KB; dword pitch 133 == 5 mod 32
    half_t (*hs)[66] = (half_t(*)[66])&xT[0][0];   // epilogue alias

    const int n0 = blockIdx.x * 64;
    const int b  = blockIdx.y;
    const int sel = blockIdx.z;
    const float* in = sel ? y : x;
    const half_t* Wf = sel ? Wfy : Wfx;
    const half_t* Wg = sel ? Wgy : Wgx;
    const half_t* Wh = sel ? Why : Whx;
    const float*  bf = sel ? bfy : bfx;
    const float*  bg = sel ? bgy : bgx;
    const float*  bh = sel ? bhy : bhx;
    half_t* fT = sel ? fyT : fxT;
    half_t* gT = sel ? gyT : gxT;
    half_t* h  = sel ? hy : hx;

    const int t = threadIdx.x;
    const int w = t >> 6, lane = t & 63;
    const int q = lane >> 4, mc = lane & 15;

    // ---- stage 1: coalesced fp32 load (float4 along n) + transpose to LDS
    {
        const int n4 = t & 15;
        const int cb = t >> 4;
        const float* inb = in + (size_t)b * CC * NN + n0 + n4 * 4;
        #pragma unroll
        for (int j = 0; j < 8; ++j) {
            const int c = cb + 32 * j;
            float4 v = *(const float4*)&inb[(size_t)c * NN];
            xT[n4 * 4 + 0][c] = (half_t)v.x;
            xT[n4 * 4 + 1][c] = (half_t)v.y;
            xT[n4 * 4 + 2][c] = (half_t)v.z;
            xT[n4 * 4 + 3][c] = (half_t)v.w;
        }
    }
    __syncthreads();

    // ---- stage 2: f,g. wave w -> of = w>>1, n-half = (w&1)*32.
    {
        const int of  = w >> 1;
        const int col = (of & 1) * 16 + mc;
        const half_t* Ws = (of < 2) ? Wf : Wg;
        const float*  bs = (of < 2) ? bf : bg;
        half_t* dst = (of < 2) ? fT : gT;
        const float bv = bs[col];
        floatx4 accf[2] = {{bv, bv, bv, bv}, {bv, bv, bv, bv}};

        #pragma unroll
        for (int ks = 0; ks < 8; ++ks) {
            int k0 = ks * 32 + q * 8;
            half8 bfr = *(const half8*)&Ws[(size_t)col * CC + k0];
            #pragma unroll
            for (int e = 0; e < 2; ++e) {
                half8 af = *(const half8*)&xT[(w & 1) * 32 + e * 16 + mc][k0];
                accf[e] = __builtin_amdgcn_mfma_f32_16x16x32_f16(af, bfr, accf[e], 0, 0, 0);
            }
        }
        #pragma unroll
        for (int e = 0; e < 2; ++e)
            #pragma unroll
            for (int r = 0; r < 4; ++r) {
                int n = n0 + (w & 1) * 32 + e * 16 + q * 4 + r;
                dst[((size_t)b * NN + n) * 32 + col] = (half_t)accf[e][r];
            }
    }

    // ---- stage 3: h GEMM (wave w -> o-strip w*32), epilogue through LDS.
    {
        const int o0 = w * 32;
        floatx4 acch[2][4];
        #pragma unroll
        for (int j = 0; j < 2; ++j) {
            floatx4 bv;
            #pragma unroll
            for (int r = 0; r < 4; ++r) bv[r] = bh[o0 + j * 16 + q * 4 + r];
            #pragma unroll
            for (int i = 0; i < 4; ++i) acch[j][i] = bv;
        }

        #pragma unroll
        for (int ks = 0; ks < 8; ++ks) {
            int k0 = ks * 32 + q * 8;
            half8 a0 = *(const half8*)&Wh[(size_t)(o0 + mc) * CC + k0];
            half8 a1 = *(const half8*)&Wh[(size_t)(o0 + 16 + mc) * CC + k0];
            #pragma unroll
            for (int i = 0; i < 4; ++i) {
                half8 bfr = *(const half8*)&xT[i * 16 + mc][k0];
                acch[0][i] = __builtin_amdgcn_mfma_f32_16x16x32_f16(a0, bfr, acch[0][i], 0, 0, 0);
                acch[1][i] = __builtin_amdgcn_mfma_f32_16x16x32_f16(a1, bfr, acch[1][i], 0, 0, 0);
            }
        }

        __syncthreads();     // all xT reads done; safe to overwrite as hs
        #pragma unroll
        for (int j = 0; j < 2; ++j)
            #pragma unroll
            for (int i = 0; i < 4; ++i)
                #pragma unroll
                for (int r = 0; r < 4; ++r) {
                    int o = o0 + j * 16 + q * 4 + r;
                    hs[o][i * 16 + mc] = (half_t)acch[j][i][r];
                }
        __syncthreads();     // hs complete

        const int ro  = t >> 1;
        const int nh2 = (t & 1) * 32;
        half_t* hb = h + (size_t)b * CC * NN;
        #pragma unroll
        for (int k2 = 0; k2 < 4; ++k2) {
            half8 v = *(const half8*)&hs[ro][nh2 + k2 * 8];
            *(half8*)&hb[(size_t)ro * NN + n0 + nh2 + k2 * 8] = v;
        }
    }
}

// ---------------------------------------------------------------------------
// stats: Llog2[n] = -log2( sum_m exp(S[n,m]) ). grid (128, 4, 2).
// ---------------------------------------------------------------------------
__global__ __launch_bounds__(256)
void stats_kernel(const half_t* __restrict__ fT0, const half_t* __restrict__ gT0,
                  const half_t* __restrict__ fT1, const half_t* __restrict__ gT1,
                  float* __restrict__ L0, float* __restrict__ L1)
{
    __shared__ float red_l[4][32];
    const int b  = blockIdx.y;
    const int sel = blockIdx.z;
    const half_t* fT = sel ? fT1 : fT0;
    const half_t* gT = sel ? gT1 : gT0;
    float* Lout = sel ? L1 : L0;

    const int n0 = blockIdx.x * 32;
    const int t  = threadIdx.x;
    const int w = t >> 6, lane = t & 63, q = lane >> 4, mc = lane & 15;
    const half_t* fTb = fT + (size_t)b * NN * 32;
    const half_t* gTb = gT + (size_t)b * NN * 32;

    half8 a0 = *(const half8*)&fTb[(size_t)(n0 + mc) * 32 + q * 8];
    half8 a1 = *(const half8*)&fTb[(size_t)(n0 + 16 + mc) * 32 + q * 8];

    float l0[4] = {0.f, 0.f, 0.f, 0.f}, l1[4] = {0.f, 0.f, 0.f, 0.f};
    for (int it = 0; it < NN / 64; ++it) {
        int m = (it * 4 + w) * 16 + mc;
        half8 bfr = *(const half8*)&gTb[(size_t)m * 32 + q * 8];
        floatx4 S0 = __builtin_amdgcn_mfma_f32_16x16x32_f16(a0, bfr, (floatx4){0.f,0.f,0.f,0.f}, 0, 0, 0);
        floatx4 S1 = __builtin_amdgcn_mfma_f32_16x16x32_f16(a1, bfr, (floatx4){0.f,0.f,0.f,0.f}, 0, 0, 0);
        #pragma unroll
        for (int r = 0; r < 4; ++r) { l0[r] += __expf(S0[r]); l1[r] += __expf(S1[r]); }
    }
    #pragma unroll
    for (int r = 0; r < 4; ++r) {
        #pragma unroll
        for (int off = 1; off < 16; off <<= 1) {
            l0[r] += __shfl_xor(l0[r], off);
            l1[r] += __shfl_xor(l1[r], off);
        }
    }
    if (mc == 0)
        #pragma unroll
        for (int r = 0; r < 4; ++r) {
            red_l[w][q * 4 + r]      = l0[r];
            red_l[w][16 + q * 4 + r] = l1[r];
        }
    __syncthreads();
    if (t < 32) {
        float L = red_l[0][t] + red_l[1][t] + red_l[2][t] + red_l[3][t];
        Lout[(size_t)b * NN + n0 + t] = -log2f(L);
    }
}

// ---------------------------------------------------------------------------
// pv: out[c,m] = src[c,m] + gamma * sum_n h[c,n] * exp2(S*log2e + Llog2[n]).
// v11 = v7 with n-tile 64 -> 128: 32 iterations (barrier count halved),
// same splits/math/schedule. grid (32, 8): block = 128m x 256c, 8 waves,
// 1 block/CU, LDS 136 KB (h_lds 68K + PT dbuf 68K, pitch 136 halves).
// S: wave -> smg=(w>>1)*32 m, snh=(w&1)*64 n: 8 MFMA16, 32 exp/lane.
// PV: wave -> cg=(w&3)*64 c, pmg=(w>>2)*64 m: 8 k-chunks, 32 reads,
// 32 MFMA32 (ratio 1.0). Merged S||PV interval, PT dbuf, depth-1 reg
// pipeline, setprio. Accumulation order over n unchanged -> bit-identical.
// ---------------------------------------------------------------------------
__global__ __launch_bounds__(512, 2)
void pv_kernel(const half_t* __restrict__ fT0, const half_t* __restrict__ gT0,
               const half_t* __restrict__ h0, const float* __restrict__ L0,
               const float* __restrict__ src0, float* __restrict__ out0,
               const half_t* __restrict__ fT1, const half_t* __restrict__ gT1,
               const half_t* __restrict__ h1, const float* __restrict__ L1,
               const float* __restrict__ src1, float* __restrict__ out1,
               const float* __restrict__ gamma)
{
    __shared__ half_t h_lds[256][136];   // 68 KB, pitch 136 (16B-aligned)
    __shared__ half_t PT[2][128][136];   // 68 KB, double-buffered P^T[m][n]

    const int m0 = blockIdx.x * 128;
    const int b  = blockIdx.y & 3;
    const int sel = blockIdx.y >> 2;
    const half_t* fT = sel ? fT1 : fT0;
    const half_t* gT = sel ? gT1 : gT0;
    const half_t* h  = sel ? h1 : h0;
    const float*  Lg = sel ? L1 : L0;
    const float*  src = sel ? src1 : src0;
    float* out = sel ? out1 : out0;

    const int t = threadIdx.x;
    const int w = t >> 6, lane = t & 63;
    const int q = lane >> 4, mc = lane & 15;
    const int l5 = lane >> 5, l31 = lane & 31;

    const int smg = (w >> 1) * 32;     // S m-group (2 x 16 rows)
    const int snh = (w & 1) * 64;      // S n-half (4 x 16 cols)
    const int cg  = (w & 3) * 64;      // PV c-group
    const int pmg = (w >> 2) * 64;     // PV m-group

    const half_t* fTb = fT + (size_t)b * NN * 32;
    const half_t* gTb = gT + (size_t)b * NN * 32;
    const half_t* hb  = h + (size_t)b * CC * NN;
    const float*  Lb  = Lg + (size_t)b * NN;

    // persistent S B-frags: m = m0 + smg + u*16 + mc
    half8 gS[2];
    gS[0] = *(const half8*)&gTb[(size_t)(m0 + smg + mc) * 32 + q * 8];
    gS[1] = *(const half8*)&gTb[(size_t)(m0 + smg + 16 + mc) * 32 + q * 8];

    // h staging: thread covers rows srow + 32*i (i=0..7), chunk sch (16B)
    const int srow = t >> 4;    // 0..31
    const int sch  = t & 15;    // 0..15

    // lane base pointers
    const half_t* hP = hb + (size_t)srow * NN + sch * 8;        // + 32*i*NN + nt
    const half_t* fP = fTb + (size_t)(snh + mc) * 32 + q * 8;   // + (nt + s*16)*32
    const float*  lP = Lb + snh + q * 4;                        // + nt + s*16

    floatx16 acc[2][2];
    #pragma unroll
    for (int a = 0; a < 2; ++a)
        #pragma unroll
        for (int ms = 0; ms < 2; ++ms)
            #pragma unroll
            for (int r = 0; r < 16; ++r) acc[a][ms][r] = 0.f;

    half8 hpre[8];              // h tile in flight (stage next iter)
    half8 fu[4], ff[4];         // f: in-use (S this iter), in-flight
    floatx4 lvu[4], lvf[4];

    // ---- prologue: P(0) -> PT[0]; hpre(0); f(1)/lv(1) -> fu/lvu
    {
        half8 f0[4]; floatx4 l0[4];
        #pragma unroll
        for (int s = 0; s < 4; ++s) {
            f0[s] = *(const half8*)&fP[(size_t)(s * 16) * 32];
            l0[s] = *(const floatx4*)&lP[s * 16];
        }
        #pragma unroll
        for (int u = 0; u < 2; ++u)
            #pragma unroll
            for (int s = 0; s < 4; ++s) {
                floatx4 S = __builtin_amdgcn_mfma_f32_16x16x32_f16(
                    f0[s], gS[u], (floatx4){0.f, 0.f, 0.f, 0.f}, 0, 0, 0);
                half4 p;
                p[0] = (half_t)exp2f(fmaf(S[0], 1.44269504f, l0[s][0]));
                p[1] = (half_t)exp2f(fmaf(S[1], 1.44269504f, l0[s][1]));
                p[2] = (half_t)exp2f(fmaf(S[2], 1.44269504f, l0[s][2]));
                p[3] = (half_t)exp2f(fmaf(S[3], 1.44269504f, l0[s][3]));
                *(half4*)&PT[0][smg + u * 16 + mc][snh + s * 16 + q * 4] = p;
            }
    }
    #pragma unroll
    for (int i = 0; i < 8; ++i)
        hpre[i] = *(const half8*)&hP[(size_t)(32 * i) * NN];
    #pragma unroll
    for (int s = 0; s < 4; ++s) {
        fu[s]  = *(const half8*)&fP[(size_t)(128 + s * 16) * 32];
        lvu[s] = *(const floatx4*)&lP[128 + s * 16];
    }

    #pragma unroll 2
    for (int T = 0; T < NN / 128; ++T) {     // 32 iterations
        const int cur = T & 1, nxt = cur ^ 1;

        __syncthreads();              // A: prev PV's h_lds reads done; loads landed
        #pragma unroll
        for (int i = 0; i < 8; ++i)
            *(half8*)&h_lds[srow + 32 * i][sch * 8] = hpre[i];
        __syncthreads();              // B: h_lds(T) visible

        // ---- issue loads: h(T+1), f(T+2)/L(T+2) (drain at next barA)
        int ntn  = (T + 1) * 128; if (ntn  >= NN) ntn  = 0;
        int ntn2 = (T + 2) * 128; if (ntn2 >= NN) ntn2 -= NN;
        #pragma unroll
        for (int i = 0; i < 8; ++i)
            hpre[i] = *(const half8*)&hP[(size_t)(32 * i) * NN + ntn];
        #pragma unroll
        for (int s = 0; s < 4; ++s) {
            ff[s]  = *(const half8*)&fP[(size_t)(ntn2 + s * 16) * 32];
            lvf[s] = *(const floatx4*)&lP[ntn2 + s * 16];
        }

        // ---- S(T+1): wave's 32m x 64n strip -> PT[nxt] (VALU-heavy)
        #pragma unroll
        for (int u = 0; u < 2; ++u)
            #pragma unroll
            for (int s = 0; s < 4; ++s) {
                floatx4 S = __builtin_amdgcn_mfma_f32_16x16x32_f16(
                    fu[s], gS[u], (floatx4){0.f, 0.f, 0.f, 0.f}, 0, 0, 0);
                half4 p;
                p[0] = (half_t)exp2f(fmaf(S[0], 1.44269504f, lvu[s][0]));
                p[1] = (half_t)exp2f(fmaf(S[1], 1.44269504f, lvu[s][1]));
                p[2] = (half_t)exp2f(fmaf(S[2], 1.44269504f, lvu[s][2]));
                p[3] = (half_t)exp2f(fmaf(S[3], 1.44269504f, lvu[s][3]));
                *(half4*)&PT[nxt][smg + u * 16 + mc][snh + s * 16 + q * 4] = p;
            }

        // ---- PV(T): wave's 64c x 64m tile; 8 k-chunks of 16
        __builtin_amdgcn_s_setprio(1);
        #pragma unroll
        for (int ch = 0; ch < 8; ++ch) {
            half8 A0 = *(const half8*)&h_lds[cg + l31][ch * 16 + l5 * 8];
            half8 A1 = *(const half8*)&h_lds[cg + 32 + l31][ch * 16 + l5 * 8];
            half8 B0 = *(const half8*)&PT[cur][pmg + l31][ch * 16 + l5 * 8];
            half8 B1 = *(const half8*)&PT[cur][pmg + 32 + l31][ch * 16 + l5 * 8];
            acc[0][0] = __builtin_amdgcn_mfma_f32_32x32x16_f16(A0, B0, acc[0][0], 0, 0, 0);
            acc[0][1] = __builtin_amdgcn_mfma_f32_32x32x16_f16(A0, B1, acc[0][1], 0, 0, 0);
            acc[1][0] = __builtin_amdgcn_mfma_f32_32x32x16_f16(A1, B0, acc[1][0], 0, 0, 0);
            acc[1][1] = __builtin_amdgcn_mfma_f32_32x32x16_f16(A1, B1, acc[1][1], 0, 0, 0);
        }
        __builtin_amdgcn_s_setprio(0);

        // rotate f/L pipeline (hpre rotates in place)
        #pragma unroll
        for (int s = 0; s < 4; ++s) { fu[s] = ff[s]; lvu[s] = lvf[s]; }
    }

    // ---- epilogue: out = src + gamma * acc (D: col=l31->m, row pattern->c)
    const float gm = gamma[0];
    const float* srcb = src + (size_t)b * CC * NN;
    float* outb = out + (size_t)b * CC * NN;
    #pragma unroll
    for (int a = 0; a < 2; ++a)
        #pragma unroll
        for (int ms = 0; ms < 2; ++ms) {
            const int m = m0 + pmg + ms * 32 + l31;
            #pragma unroll
            for (int r = 0; r < 16; ++r) {
                int c = cg + a * 32 + (r & 3) + 8 * (r >> 2) + 4 * l5;
                size_t idx = (size_t)c * NN + m;
                outb[idx] = fmaf(gm, acc[a][ms][r], srcb[idx]);
            }
        }
}

// ---------------------------------------------------------------------------
extern "C" void kernel_launch(void* const* d_in, const int* in_sizes, int n_in,
                              void* d_out, int out_size, void* d_ws, size_t ws_size,
                              hipStream_t stream)
{
    const float* x   = (const float*)d_in[0];
    const float* y   = (const float*)d_in[1];
    const float* Wfx = (const float*)d_in[2];
    const float* bfx = (const float*)d_in[3];
    const float* Wgx = (const float*)d_in[4];
    const float* bgx = (const float*)d_in[5];
    const float* Whx = (const float*)d_in[6];
    const float* bhx = (const float*)d_in[7];
    const float* Wfy = (const float*)d_in[8];
    const float* bfy = (const float*)d_in[9];
    const float* Wgy = (const float*)d_in[10];
    const float* bgy = (const float*)d_in[11];
    const float* Why = (const float*)d_in[12];
    const float* bhy = (const float*)d_in[13];
    const float* gam = (const float*)d_in[14];

    const size_t SZ_XT = (size_t)BB * NN * CC;   // 4,194,304 halves
    const size_t SZ_FG = (size_t)BB * NN * 32;   // 524,288 halves
    half_t* xTx   = (half_t*)d_ws;               // (unused, layout kept)
    half_t* xTy   = xTx + SZ_XT;
    half_t* hx    = xTy + SZ_XT;                 // plain h[c][n]
    half_t* hy    = hx + SZ_XT;                  // plain h[c][n]
    half_t* fxT   = hy + SZ_XT;
    half_t* gxT   = fxT + SZ_FG;
    half_t* fyT   = gxT + SZ_FG;
    half_t* gyT   = fyT + SZ_FG;
    half_t* Wfx_h = gyT + SZ_FG;
    half_t* Wgx_h = Wfx_h + 32 * CC;
    half_t* Wfy_h = Wgx_h + 32 * CC;
    half_t* Wgy_h = Wfy_h + 32 * CC;
    half_t* Whx_h = Wgy_h + 32 * CC;
    half_t* Why_h = Whx_h + CC * CC;
    float*  Lx    = (float*)(Why_h + CC * CC);
    float*  Ly    = Lx + (size_t)BB * NN;

    float* outx = (float*)d_out;
    float* outy = outx + (size_t)BB * CC * NN;

    cvt_w_kernel<<<dim3(64, 6), 256, 0, stream>>>(Wfx, Wgx, Whx, Wfy, Wgy, Why,
                                                  Wfx_h, Wgx_h, Whx_h, Wfy_h, Wgy_h, Why_h);

    prep_kernel<<<dim3(64, 4, 2), 512, 0, stream>>>(
        x, y, Wfx_h, Wgx_h, Whx_h, Wfy_h, Wgy_h, Why_h,
        bfx, bgx, bhx, bfy, bgy, bhy,
        fxT, gxT, hx, fyT, gyT, hy);

    // att_x rows: fy vs gx -> Lx ; att_y rows: fx vs gy -> Ly
    stats_kernel<<<dim3(128, 4, 2), 256, 0, stream>>>(fyT, gxT, fxT, gyT, Lx, Ly);

    pv_kernel<<<dim3(32, 8), 512, 0, stream>>>(
        fyT, gxT, hx, Lx, x, outx,
        fxT, gyT, hy, Ly, y, outy, gam);
}